// Round 1
// baseline (93.691 us; speedup 1.0000x reference)
//
#include <hip/hip_runtime.h>

// x: [B=32, C=128, H=128, W=128] f32
// out: [B, 3C, 64, 64] f32 — [vals | pos_h | pos_w] along channel dim
// K=2 non-overlapping max pool + argmax position decode.

__global__ __launch_bounds__(256) void pap_kernel(const float* __restrict__ x,
                                                  float* __restrict__ out) {
    constexpr int C = 128, H = 128, W = 128;
    constexpr int OH = 64, OW = 64;
    constexpr int OWP = OW / 2;                 // thread covers 2 output cols
    constexpr int total = 32 * C * OH * OWP;    // 8,388,608 threads of work
    constexpr float invH = 1.0f / (float)H;
    constexpr float invW = 1.0f / (float)W;

    for (int t = blockIdx.x * blockDim.x + threadIdx.x; t < total;
         t += gridDim.x * blockDim.x) {
        const int owp = t & (OWP - 1);          // 0..31
        const int oh  = (t >> 5) & (OH - 1);    // 0..63
        const int bc  = t >> 11;                // b*C + c, 0..4095
        const int c   = bc & (C - 1);
        const int b   = bc >> 7;

        const size_t rowbase = ((size_t)bc * H + 2 * oh) * W + 4 * owp;
        const float4 r0 = *reinterpret_cast<const float4*>(x + rowbase);
        const float4 r1 = *reinterpret_cast<const float4*>(x + rowbase + W);

        float2 vals, ph, pw;
        // window 0: elements (r0.x, r0.y, r1.x, r1.y) in row-major window order
        {
            float v = r0.x; int idx = 0;
            if (r0.y > v) { v = r0.y; idx = 1; }
            if (r1.x > v) { v = r1.x; idx = 2; }
            if (r1.y > v) { v = r1.y; idx = 3; }
            vals.x = v;
            ph.x = (float)(2 * oh + (idx >> 1)) * invH;
            pw.x = (float)(4 * owp + (idx & 1)) * invW;
        }
        // window 1: elements (r0.z, r0.w, r1.z, r1.w)
        {
            float v = r0.z; int idx = 0;
            if (r0.w > v) { v = r0.w; idx = 1; }
            if (r1.z > v) { v = r1.z; idx = 2; }
            if (r1.w > v) { v = r1.w; idx = 3; }
            vals.y = v;
            ph.y = (float)(2 * oh + (idx >> 1)) * invH;
            pw.y = (float)(4 * owp + 2 + (idx & 1)) * invW;
        }

        const size_t plane = (size_t)C * OH * OW;                 // 524288
        const size_t obase = (((size_t)b * (3 * C) + c) * OH + oh) * OW + 2 * owp;
        *reinterpret_cast<float2*>(out + obase)             = vals;
        *reinterpret_cast<float2*>(out + obase + plane)     = ph;
        *reinterpret_cast<float2*>(out + obase + 2 * plane) = pw;
    }
}

extern "C" void kernel_launch(void* const* d_in, const int* in_sizes, int n_in,
                              void* d_out, int out_size, void* d_ws, size_t ws_size,
                              hipStream_t stream) {
    const float* x = (const float*)d_in[0];
    float* out = (float*)d_out;
    const int blocks = 2048;   // 256 CUs × 8 blocks/CU; grid-stride covers the rest
    pap_kernel<<<blocks, 256, 0, stream>>>(x, out);
}

// Round 3
// 85.337 us; speedup vs baseline: 1.0979x; 1.0979x over previous
//
#include <hip/hip_runtime.h>

// x: [B=32, C=128, H=128, W=128] f32
// out: [B, 3C, 64, 64] f32 — [vals | pos_h | pos_w] along channel dim
// K=2 non-overlapping max pool + argmax position decode (first-max ties).
// Each thread: 4 output windows -> 4x 16B loads, 3x 16B stores, nontemporal.

typedef float f32x4 __attribute__((ext_vector_type(4)));

__global__ __launch_bounds__(256) void pap_kernel(const float* __restrict__ x,
                                                  float* __restrict__ out) {
    constexpr int C = 128, H = 128, W = 128;
    constexpr int OH = 64, OW = 64;
    constexpr int OWQ = OW / 4;                 // thread covers 4 output cols
    constexpr int total = 32 * C * OH * OWQ;    // 4,194,304 work items
    constexpr float invH = 1.0f / (float)H;
    constexpr float invW = 1.0f / (float)W;

    for (int t = blockIdx.x * blockDim.x + threadIdx.x; t < total;
         t += gridDim.x * blockDim.x) {
        const int owq = t & (OWQ - 1);          // 0..15
        const int oh  = (t >> 4) & (OH - 1);    // 0..63
        const int bc  = t >> 10;                // b*C + c, 0..4095
        const int c   = bc & (C - 1);
        const int b   = bc >> 7;

        const size_t rowbase = ((size_t)bc * H + 2 * oh) * W + 8 * owq;
        f32x4 r0a = __builtin_nontemporal_load(
            reinterpret_cast<const f32x4*>(x + rowbase));
        f32x4 r0b = __builtin_nontemporal_load(
            reinterpret_cast<const f32x4*>(x + rowbase + 4));
        f32x4 r1a = __builtin_nontemporal_load(
            reinterpret_cast<const f32x4*>(x + rowbase + W));
        f32x4 r1b = __builtin_nontemporal_load(
            reinterpret_cast<const f32x4*>(x + rowbase + W + 4));

        float r0[8], r1[8];
        *reinterpret_cast<f32x4*>(r0)     = r0a;
        *reinterpret_cast<f32x4*>(r0 + 4) = r0b;
        *reinterpret_cast<f32x4*>(r1)     = r1a;
        *reinterpret_cast<f32x4*>(r1 + 4) = r1b;

        float vals[4], ph[4], pw[4];
        #pragma unroll
        for (int w = 0; w < 4; ++w) {
            const float e0 = r0[2 * w], e1 = r0[2 * w + 1];
            const float e2 = r1[2 * w], e3 = r1[2 * w + 1];
            float v = e0; int idx = 0;
            if (e1 > v) { v = e1; idx = 1; }
            if (e2 > v) { v = e2; idx = 2; }
            if (e3 > v) { v = e3; idx = 3; }
            vals[w] = v;
            ph[w] = (float)(2 * oh + (idx >> 1)) * invH;
            pw[w] = (float)(8 * owq + 2 * w + (idx & 1)) * invW;
        }

        const size_t plane = (size_t)C * OH * OW;                 // 524288
        const size_t obase = (((size_t)b * (3 * C) + c) * OH + oh) * OW + 4 * owq;
        __builtin_nontemporal_store(*reinterpret_cast<f32x4*>(vals),
                                    reinterpret_cast<f32x4*>(out + obase));
        __builtin_nontemporal_store(*reinterpret_cast<f32x4*>(ph),
                                    reinterpret_cast<f32x4*>(out + obase + plane));
        __builtin_nontemporal_store(*reinterpret_cast<f32x4*>(pw),
                                    reinterpret_cast<f32x4*>(out + obase + 2 * plane));
    }
}

extern "C" void kernel_launch(void* const* d_in, const int* in_sizes, int n_in,
                              void* d_out, int out_size, void* d_ws, size_t ws_size,
                              hipStream_t stream) {
    const float* x = (const float*)d_in[0];
    float* out = (float*)d_out;
    const int blocks = 2048;   // 256 CUs × 8 blocks/CU; grid-stride covers the rest
    pap_kernel<<<blocks, 256, 0, stream>>>(x, out);
}

// Round 4
// 82.762 us; speedup vs baseline: 1.1321x; 1.0311x over previous
//
#include <hip/hip_runtime.h>

// x: [B=32, C=128, H=128, W=128] f32
// out: [B, 3C, 64, 64] f32 — [vals | pos_h | pos_w] along channel dim.
// K=2 pool + argmax position decode (first-max ties, row-major window order).
//
// Wave-tile structure: one wave-iteration = 4 consecutive input rows (one
// (b,c) image's rows 4*oh01 .. 4*oh01+3) = 2 output rows.
//   load a (dwordx4): rows 0-1 of the quad, 1024 B contiguous across the wave
//   load b (dwordx4): rows 2-3 of the quad, 1024 B contiguous
//   __shfl_xor(.,32) exchanges row halves so every lane holds its window's
//   top/bot 4 floats; lanes 0-31 -> output row 2*oh01, lanes 32-63 -> 2*oh01+1
//   stores: 3x dwordx2, each 512 B contiguous (2 adjacent 256 B output rows)

typedef float f32x4 __attribute__((ext_vector_type(4)));
typedef float f32x2 __attribute__((ext_vector_type(2)));

__global__ __launch_bounds__(256) void pap_kernel(const float* __restrict__ x,
                                                  float* __restrict__ out) {
    constexpr int C = 128, H = 128, W = 128;
    constexpr int OH = 64, OW = 64;
    constexpr float inv = 1.0f / 128.0f;
    constexpr int NTILES = 32 * C * (OH / 2);   // 131072 wave-tiles
    constexpr size_t plane = (size_t)C * OH * OW;  // 524288 floats

    const int lane = threadIdx.x & 63;
    const int wid  = (blockIdx.x * blockDim.x + threadIdx.x) >> 6;
    const int nw   = (gridDim.x * blockDim.x) >> 6;
    const bool hi  = lane >= 32;
    const int j    = lane & 31;

    for (int t = wid; t < NTILES; t += nw) {
        const int oh01 = t & 31;          // output row pair 0..31
        const int bc   = t >> 5;          // b*C + c, 0..4095

        const size_t base = (size_t)bc * (H * W) + (size_t)oh01 * (4 * W) + lane * 4;
        f32x4 la = __builtin_nontemporal_load(reinterpret_cast<const f32x4*>(x + base));
        f32x4 lb = __builtin_nontemporal_load(reinterpret_cast<const f32x4*>(x + base + 2 * W));

        // lanes 0-31 of la = quad row0, lanes 32-63 = row1; lb: rows 2,3
        float top[4], bot[4];
        #pragma unroll
        for (int k = 0; k < 4; ++k) {
            const float sa = __shfl_xor(la[k], 32, 64);   // partner's la
            const float sb = __shfl_xor(lb[k], 32, 64);   // partner's lb
            top[k] = hi ? sb : la[k];   // lo: row0 chunk, hi: row2 chunk
            bot[k] = hi ? lb[k] : sa;   // lo: row1 chunk, hi: row3 chunk
        }

        const int oh_out = 2 * oh01 + (hi ? 1 : 0);
        f32x2 vals, ph, pw;
        {   // window 0: cols 4j,4j+1 — order top0,top1,bot0,bot1
            float v = top[0]; int idx = 0;
            if (top[1] > v) { v = top[1]; idx = 1; }
            if (bot[0] > v) { v = bot[0]; idx = 2; }
            if (bot[1] > v) { v = bot[1]; idx = 3; }
            vals.x = v;
            ph.x = (float)(2 * oh_out + (idx >> 1)) * inv;
            pw.x = (float)(4 * j + (idx & 1)) * inv;
        }
        {   // window 1: cols 4j+2,4j+3
            float v = top[2]; int idx = 0;
            if (top[3] > v) { v = top[3]; idx = 1; }
            if (bot[2] > v) { v = bot[2]; idx = 2; }
            if (bot[3] > v) { v = bot[3]; idx = 3; }
            vals.y = v;
            ph.y = (float)(2 * oh_out + (idx >> 1)) * inv;
            pw.y = (float)(4 * j + 2 + (idx & 1)) * inv;
        }

        const int b_ = bc >> 7, c = bc & (C - 1);
        const size_t orow = ((size_t)(b_ * (3 * C) + c)) * (OH * OW)
                          + (size_t)oh_out * OW + 2 * j;
        __builtin_nontemporal_store(vals, reinterpret_cast<f32x2*>(out + orow));
        __builtin_nontemporal_store(ph,   reinterpret_cast<f32x2*>(out + orow + plane));
        __builtin_nontemporal_store(pw,   reinterpret_cast<f32x2*>(out + orow + 2 * plane));
    }
}

extern "C" void kernel_launch(void* const* d_in, const int* in_sizes, int n_in,
                              void* d_out, int out_size, void* d_ws, size_t ws_size,
                              hipStream_t stream) {
    const float* x = (const float*)d_in[0];
    float* out = (float*)d_out;
    const int blocks = 4096;   // 16384 waves; 131072 tiles -> 8 tiles/wave exact
    pap_kernel<<<blocks, 256, 0, stream>>>(x, out);
}